// Round 7
// baseline (919.963 us; speedup 1.0000x reference)
//
#include <hip/hip_runtime.h>

#define N_NODES 20000
#define N_EDGES 320000
#define CH 68

__device__ __forceinline__ float sigm(float x) { return 1.0f / (1.0f + __expf(-x)); }
// jax.nn.gelu approximate=True == x*sigmoid(1.5957691*(x+0.044715x^3))
__device__ __forceinline__ float gelu(float x) {
    return x * sigm(1.5957691216057308f * (x + 0.044715f * x * x * x));
}

__global__ void init_kernel(const float* __restrict__ s0, const float* __restrict__ p0,
                            float* __restrict__ s, float4* __restrict__ v4,
                            float* __restrict__ cnt) {
    int idx = blockIdx.x * 256 + threadIdx.x;
    if (idx < N_NODES * 16) s[idx] = s0[idx];
    if (idx < N_NODES) {
        v4[idx] = make_float4(p0[idx * 3], p0[idx * 3 + 1], p0[idx * 3 + 2], 0.f);
        cnt[idx] = 0.f;
    }
}

__global__ void count_kernel(const int* __restrict__ rcv, float* __restrict__ cnt) {
    int e = blockIdx.x * 256 + threadIdx.x;
    if (e < N_EDGES) unsafeAtomicAdd(&cnt[rcv[e]], 1.0f);
}

// one-block exclusive scan of cnt -> offs; zero the scatter cursors.
__global__ __launch_bounds__(1024) void scan_kernel(const float* __restrict__ cnt,
                                                    int* __restrict__ offs,
                                                    int* __restrict__ cursor) {
    __shared__ int sdata[1024];
    const int t = threadIdx.x;
    const int base = t * 20;  // 1024*20 = 20480 >= N_NODES
    int local[20];
    int sum = 0;
#pragma unroll
    for (int k = 0; k < 20; k++) {
        const int n = base + k;
        const int c = (n < N_NODES) ? (int)cnt[n] : 0;
        local[k] = sum;
        sum += c;
    }
    sdata[t] = sum;
    __syncthreads();
    for (int d = 1; d < 1024; d <<= 1) {
        const int v = (t >= d) ? sdata[t - d] : 0;
        __syncthreads();
        sdata[t] += v;
        __syncthreads();
    }
    const int pre = (t == 0) ? 0 : sdata[t - 1];
#pragma unroll
    for (int k = 0; k < 20; k++) {
        const int n = base + k;
        if (n < N_NODES) {
            offs[n] = pre + local[k];
            cursor[n] = 0;
        }
    }
}

// receiver-sorted permutation: perm[slot] = original edge id
__global__ void scatter_kernel(const int* __restrict__ rcv, const int* __restrict__ offs,
                               int* __restrict__ cursor, int* __restrict__ perm) {
    int e = blockIdx.x * 256 + threadIdx.x;
    if (e < N_EDGES) {
        const int n = rcv[e];
        const int slot = offs[n] + atomicAdd(&cursor[n], 1);
        perm[slot] = e;
    }
}

// Edge compute, weights in LDS, E=2 edges per thread.
// R6 calibrated the LDS-broadcast floor: 792 ds_read_b128/wave x ~12cy x 19.5
// waves/CU = 77 us of the 111 us dispatch. Weights have zero reuse WITHIN an
// edge; reuse is only ACROSS edges -> interleave two edges per thread so every
// weight read feeds 2 FMAs: LDS floor halves to ~38 us. launch_bounds(256,2)
// gives the allocator the full 256-VGPR budget (live set ~240).
// LDS layout: [0:1088) Ws0, [1088:1632) Wv0, [1632:2656) Ws1, [2656:3168) Wv1.
__global__ __launch_bounds__(256, 2) void edge_compute_kernel(
    const float4* __restrict__ s4, const float4* __restrict__ v4,
    const int* __restrict__ snd, const int* __restrict__ rcv,
    const int* __restrict__ perm,
    const float* __restrict__ Ws0, const float* __restrict__ bs0, const float* __restrict__ Wv0,
    const float* __restrict__ Ws1, const float* __restrict__ bs1, const float* __restrict__ Wv1,
    float* __restrict__ msg) {
    __shared__ float lW[3168];
    const int tid = threadIdx.x;
    {
        for (int idx = tid; idx < 1088; idx += 256) lW[idx] = Ws0[idx];
        for (int idx = tid; idx < 544; idx += 256) lW[1088 + idx] = Wv0[idx];
        for (int idx = tid; idx < 1024; idx += 256) lW[1632 + idx] = Ws1[idx];
        for (int idx = tid; idx < 512; idx += 256) lW[2656 + idx] = Wv1[idx];
    }
    __syncthreads();
    const float* __restrict__ lWs0 = lW;
    const float* __restrict__ lWv0 = lW + 1088;
    const float* __restrict__ lWs1 = lW + 1632;
    const float* __restrict__ lWv1 = lW + 2656;

    const int eA = blockIdx.x * 512 + tid;  // grid = 625 covers N_EDGES exactly
    const int eB = eA + 256;
    const int eidA = perm[eA], eidB = perm[eB];
    const int iA = snd[eidA], jA = rcv[eidA];
    const int iB = snd[eidB], jB = rcv[eidB];

    const float4 viA4 = v4[iA], vjA4 = v4[jA];
    const float4 viB4 = v4[iB], vjB4 = v4[jB];
    const float vi0A = viA4.x, vi1A = viA4.y, vi2A = viA4.z;
    const float vj0A = vjA4.x, vj1A = vjA4.y, vj2A = vjA4.z;
    const float vi0B = viB4.x, vi1B = viB4.y, vi2B = viB4.z;
    const float vj0B = vjB4.x, vj1B = vjB4.y, vj2B = vjB4.z;
    float a0A, a1A, a2A, a0B, a1B, a2B;
    {
        const float r0 = vi0A - vj0A, r1 = vi1A - vj1A, r2 = vi2A - vj2A;
        const float scl = 1.7320508075688772f / (sqrtf(r0 * r0 + r1 * r1 + r2 * r2) + 1e-8f);
        a0A = r0 * scl; a1A = r1 * scl; a2A = r2 * scl;
    }
    {
        const float r0 = vi0B - vj0B, r1 = vi1B - vj1B, r2 = vi2B - vj2B;
        const float scl = 1.7320508075688772f / (sqrtf(r0 * r0 + r1 * r1 + r2 * r2) + 1e-8f);
        a0B = r0 * scl; a1B = r1 * scl; a2B = r2 * scl;
    }

    float xsA[32], xsB[32];
    {
        float4 A = s4[iA * 4 + 0], B = s4[iA * 4 + 1], C = s4[iA * 4 + 2], D = s4[iA * 4 + 3];
        xsA[0] = A.x; xsA[1] = A.y; xsA[2] = A.z; xsA[3] = A.w;
        xsA[4] = B.x; xsA[5] = B.y; xsA[6] = B.z; xsA[7] = B.w;
        xsA[8] = C.x; xsA[9] = C.y; xsA[10] = C.z; xsA[11] = C.w;
        xsA[12] = D.x; xsA[13] = D.y; xsA[14] = D.z; xsA[15] = D.w;
        A = s4[jA * 4 + 0]; B = s4[jA * 4 + 1]; C = s4[jA * 4 + 2]; D = s4[jA * 4 + 3];
        xsA[16] = A.x; xsA[17] = A.y; xsA[18] = A.z; xsA[19] = A.w;
        xsA[20] = B.x; xsA[21] = B.y; xsA[22] = B.z; xsA[23] = B.w;
        xsA[24] = C.x; xsA[25] = C.y; xsA[26] = C.z; xsA[27] = C.w;
        xsA[28] = D.x; xsA[29] = D.y; xsA[30] = D.z; xsA[31] = D.w;
        A = s4[iB * 4 + 0]; B = s4[iB * 4 + 1]; C = s4[iB * 4 + 2]; D = s4[iB * 4 + 3];
        xsB[0] = A.x; xsB[1] = A.y; xsB[2] = A.z; xsB[3] = A.w;
        xsB[4] = B.x; xsB[5] = B.y; xsB[6] = B.z; xsB[7] = B.w;
        xsB[8] = C.x; xsB[9] = C.y; xsB[10] = C.z; xsB[11] = C.w;
        xsB[12] = D.x; xsB[13] = D.y; xsB[14] = D.z; xsB[15] = D.w;
        A = s4[jB * 4 + 0]; B = s4[jB * 4 + 1]; C = s4[jB * 4 + 2]; D = s4[jB * 4 + 3];
        xsB[16] = A.x; xsB[17] = A.y; xsB[18] = A.z; xsB[19] = A.w;
        xsB[20] = B.x; xsB[21] = B.y; xsB[22] = B.z; xsB[23] = B.w;
        xsB[24] = C.x; xsB[25] = C.y; xsB[26] = C.z; xsB[27] = C.w;
        xsB[28] = D.x; xsB[29] = D.y; xsB[30] = D.z; xsB[31] = D.w;
    }
    const float diA = vi0A * a0A + vi1A * a1A + vi2A * a2A;
    const float djA = vj0A * a0A + vj1A * a1A + vj2A * a2A;
    const float diB = vi0B * a0B + vi1B * a1B + vi2B * a2B;
    const float djB = vj0B * a0B + vj1B * a1B + vj2B * a2B;

    // ---- TPLG 0 ----
    float slA[32], slB[32];
#pragma unroll
    for (int o = 0; o < 32; o++) {
        const float b = bs0[o], w32 = lWs0[1024 + o], w33 = lWs0[1056 + o];
        slA[o] = b + diA * w32 + djA * w33;
        slB[o] = b + diB * w32 + djB * w33;
    }
#pragma unroll
    for (int p = 0; p < 32; p++) {
        const float xA = xsA[p], xB = xsB[p];
#pragma unroll
        for (int o = 0; o < 32; o++) {
            const float w = lWs0[p * 32 + o];
            slA[o] += xA * w; slB[o] += xB * w;
        }
    }
    float alA[16], alB[16];
#pragma unroll
    for (int q = 0; q < 16; q++) { alA[q] = 0.f; alB[q] = 0.f; }
#pragma unroll
    for (int p = 0; p < 32; p++) {
        const float xA = xsA[p], xB = xsB[p];
#pragma unroll
        for (int q = 0; q < 16; q++) {
            const float w = lWv0[p * 16 + q];
            alA[q] += xA * w; alB[q] += xB * w;
        }
    }
    float msA[16], mv0A[16], mv1A[16], mv2A[16];
    float msB[16], mv0B[16], mv1B[16], mv2B[16];
#pragma unroll
    for (int q = 0; q < 16; q++) {
        const float w32 = lWv0[512 + q], w33 = lWv0[528 + q];
        const float gA = sigm(slA[q]);
        mv0A[q] = (alA[q] * a0A + w32 * vi0A + w33 * vj0A) * gA;
        mv1A[q] = (alA[q] * a1A + w32 * vi1A + w33 * vj1A) * gA;
        mv2A[q] = (alA[q] * a2A + w32 * vi2A + w33 * vj2A) * gA;
        const float gB = sigm(slB[q]);
        mv0B[q] = (alB[q] * a0B + w32 * vi0B + w33 * vj0B) * gB;
        mv1B[q] = (alB[q] * a1B + w32 * vi1B + w33 * vj1B) * gB;
        mv2B[q] = (alB[q] * a2B + w32 * vi2B + w33 * vj2B) * gB;
    }
#pragma unroll
    for (int p = 0; p < 16; p++) { msA[p] = gelu(slA[16 + p]); msB[p] = gelu(slB[16 + p]); }

    // ---- TPLG 1 ----
    float sl2A[32], sl2B[32];
#pragma unroll
    for (int o = 0; o < 32; o++) { const float b = bs1[o]; sl2A[o] = b; sl2B[o] = b; }
#pragma unroll
    for (int p = 0; p < 16; p++) {
        const float xA = msA[p], xB = msB[p];
#pragma unroll
        for (int o = 0; o < 32; o++) {
            const float w = lWs1[p * 32 + o];
            sl2A[o] += xA * w; sl2B[o] += xB * w;
        }
    }
#pragma unroll
    for (int q = 0; q < 16; q++) {
        const float xA = mv0A[q] * a0A + mv1A[q] * a1A + mv2A[q] * a2A;
        const float xB = mv0B[q] * a0B + mv1B[q] * a1B + mv2B[q] * a2B;
#pragma unroll
        for (int o = 0; o < 32; o++) {
            const float w = lWs1[(16 + q) * 32 + o];
            sl2A[o] += xA * w; sl2B[o] += xB * w;
        }
    }

    // ---- stream message rows; scalars first (frees sl2[16..31]) ----
    float4* mrowA = (float4*)(msg + (size_t)eA * CH);
    float4* mrowB = (float4*)(msg + (size_t)eB * CH);
    mrowA[0] = make_float4(gelu(sl2A[16]), gelu(sl2A[17]), gelu(sl2A[18]), gelu(sl2A[19]));
    mrowA[1] = make_float4(gelu(sl2A[20]), gelu(sl2A[21]), gelu(sl2A[22]), gelu(sl2A[23]));
    mrowA[2] = make_float4(gelu(sl2A[24]), gelu(sl2A[25]), gelu(sl2A[26]), gelu(sl2A[27]));
    mrowA[3] = make_float4(gelu(sl2A[28]), gelu(sl2A[29]), gelu(sl2A[30]), gelu(sl2A[31]));
    mrowB[0] = make_float4(gelu(sl2B[16]), gelu(sl2B[17]), gelu(sl2B[18]), gelu(sl2B[19]));
    mrowB[1] = make_float4(gelu(sl2B[20]), gelu(sl2B[21]), gelu(sl2B[22]), gelu(sl2B[23]));
    mrowB[2] = make_float4(gelu(sl2B[24]), gelu(sl2B[25]), gelu(sl2B[26]), gelu(sl2B[27]));
    mrowB[3] = make_float4(gelu(sl2B[28]), gelu(sl2B[29]), gelu(sl2B[30]), gelu(sl2B[31]));
#pragma unroll
    for (int qg = 0; qg < 4; qg++) {
        float tA[12], tB[12];
#pragma unroll
        for (int qq = 0; qq < 4; qq++) {
            const int q = qg * 4 + qq;
            float beA = 0.f, beB = 0.f;
#pragma unroll
            for (int p = 0; p < 16; p++) {
                const float w = lWv1[p * 16 + q];
                beA += msA[p] * w; beB += msB[p] * w;
            }
            float u0A = beA * a0A, u1A = beA * a1A, u2A = beA * a2A;
            float u0B = beB * a0B, u1B = beB * a1B, u2B = beB * a2B;
#pragma unroll
            for (int p = 0; p < 16; p++) {
                const float w = lWv1[(16 + p) * 16 + q];
                u0A += mv0A[p] * w; u1A += mv1A[p] * w; u2A += mv2A[p] * w;
                u0B += mv0B[p] * w; u1B += mv1B[p] * w; u2B += mv2B[p] * w;
            }
            const float gA = sigm(sl2A[q]), gB = sigm(sl2B[q]);
            tA[qq * 3 + 0] = u0A * gA; tA[qq * 3 + 1] = u1A * gA; tA[qq * 3 + 2] = u2A * gA;
            tB[qq * 3 + 0] = u0B * gB; tB[qq * 3 + 1] = u1B * gB; tB[qq * 3 + 2] = u2B * gB;
        }
        mrowA[4 + qg * 3 + 0] = make_float4(tA[0], tA[1], tA[2], tA[3]);
        mrowA[4 + qg * 3 + 1] = make_float4(tA[4], tA[5], tA[6], tA[7]);
        mrowA[4 + qg * 3 + 2] = make_float4(tA[8], tA[9], tA[10], tA[11]);
        mrowB[4 + qg * 3 + 0] = make_float4(tB[0], tB[1], tB[2], tB[3]);
        mrowB[4 + qg * 3 + 1] = make_float4(tB[4], tB[5], tB[6], tB[7]);
        mrowB[4 + qg * 3 + 2] = make_float4(tB[8], tB[9], tB[10], tB[11]);
    }
    mrowA[16] = make_float4(a0A, a1A, a2A, 0.f);
    mrowB[16] = make_float4(a0B, a1B, a2B, 0.f);
}

// Gather-aggregate: node n's messages are rows offs[n]..offs[n]+cnt[n]-1,
// contiguous (receiver-sorted). One thread per (node, channel). No atomics.
__global__ __launch_bounds__(256) void agg_kernel(const float* __restrict__ msg,
                                                  const float* __restrict__ cnt,
                                                  const int* __restrict__ offs,
                                                  float* __restrict__ agg) {
    const int id = blockIdx.x * 256 + threadIdx.x;
    if (id >= N_NODES * CH) return;
    const int n = id / CH;
    const int c = id - n * CH;
    const int deg = (int)cnt[n];
    const float* p = msg + (size_t)offs[n] * CH + c;
    float acc = 0.f;
    int r = 0;
    for (; r + 4 <= deg; r += 4) {
        acc += p[(size_t)(r + 0) * CH] + p[(size_t)(r + 1) * CH] +
               p[(size_t)(r + 2) * CH] + p[(size_t)(r + 3) * CH];
    }
    for (; r < deg; r++) acc += p[(size_t)r * CH];
    agg[id] = acc;
}

// 256 threads = 4 waves; block handles 64 nodes; wave w owns channel slice c/d in [4w,4w+4) (+16 on w3).
// Node weights staged per-b into LDS: the R6 node dispatch (~55 us) is ~exactly
// the s_load latency chain (~310 batches x ~430 cy at 1 wave/SIMD, grid=313
// blocks -> 1.2 blocks/CU; VALU work is only ~2 us). Same medicine as the edge
// kernel: LDS broadcast reads pipeline under lgkmcnt.
__global__ __launch_bounds__(256, 2) void node_kernel(
    float* __restrict__ s, float4* __restrict__ v4,
    float* __restrict__ agg, const float* __restrict__ cntb,
    const float* __restrict__ nWs, const float* __restrict__ nbs, const float* __restrict__ nWv,
    const float* __restrict__ fWs, const float* __restrict__ fbs, const float* __restrict__ fWv,
    float* __restrict__ out) {
    __shared__ float nsl[64 * 17];       // per-node ns, stride 17 (conflict-free)
    __shared__ float part[21 * 256];     // partials: [t][w][lane]
    __shared__ float lw[289 * 17 + 289]; // current b: Ws then Wv (20.8 KB)
    __shared__ float lf[256];            // fWs
    const int tid = threadIdx.x;
    const int lane = tid & 63;
    const int w = tid >> 6;
    const int n0 = blockIdx.x * 64 + lane;
    const bool valid = n0 < N_NODES;
    const int n = valid ? n0 : 0;
    const float inv = 1.0f / 319999.0f;  // 1/(E-1)
    const float cnt = cntb[n];
    const float f = inv / fmaxf(cnt, 1.0f);
    float* ag = agg + n * CH;
    const int c0 = w * 4;
    const bool w3 = (w == 3);

    if (tid < 256) lf[tid] = fWs[tid];

    float yso[4];
#pragma unroll
    for (int k = 0; k < 4; k++) yso[k] = ag[c0 + k] * f;
    const float ys16 = cnt * f;
    float yvo[4][3];
#pragma unroll
    for (int k = 0; k < 4; k++) {
        const int d = c0 + k;
        yvo[k][0] = ag[16 + d * 3 + 0] * f;
        yvo[k][1] = ag[16 + d * 3 + 1] * f;
        yvo[k][2] = ag[16 + d * 3 + 2] * f;
    }
    float yv16[3] = {ag[64] * f, ag[65] * f, ag[66] * f};
    const float4 nvv = v4[n];
    float nv0 = nvv.x, nv1 = nvv.y, nv2 = nvv.z;

    if (w == 0) {
        const float4* srow = (const float4*)(s + n * 16);
        const float4 A = srow[0], B = srow[1], C = srow[2], D = srow[3];
        float* p = nsl + lane * 17;
        p[0] = A.x; p[1] = A.y; p[2] = A.z; p[3] = A.w;
        p[4] = B.x; p[5] = B.y; p[6] = B.z; p[7] = B.w;
        p[8] = C.x; p[9] = C.y; p[10] = C.z; p[11] = C.w;
        p[12] = D.x; p[13] = D.y; p[14] = D.z; p[15] = D.w;
    }

    float nsreg[16];
#pragma unroll 1
    for (int b = 0; b < 2; b++) {
        // stage this b's weights (all waves have finished reading the previous
        // b's lw before the loop-end __syncthreads below; first iter covered by
        // the same barrier staged here)
        for (int idx = tid; idx < 289 * 17; idx += 256) lw[idx] = nWs[b * 289 * 17 + idx];
        for (int idx = tid; idx < 289; idx += 256) lw[289 * 17 + idx] = nWv[b * 289 + idx];
        __syncthreads();
        const float* W = lw;
        const float* Wv = lw + 289 * 17;
        const float* bb = nbs + b * 17;
        float acc[17];
#pragma unroll
        for (int o = 0; o < 17; o++) acc[o] = (w == 0) ? bb[o] : 0.f;
        float gam[4] = {0.f, 0.f, 0.f, 0.f};
        float gam16 = 0.f;
#pragma unroll 2
        for (int a = 0; a < 16; a++) {
            const float xa = nsl[lane * 17 + a];
            const float* Wa = W + (a * 17 + c0) * 17;
#pragma unroll
            for (int k = 0; k < 4; k++) {
                const float cf = xa * yso[k];
#pragma unroll
                for (int o = 0; o < 17; o++) acc[o] += cf * Wa[k * 17 + o];
            }
            const float* Wva = Wv + a * 17 + c0;
#pragma unroll
            for (int k = 0; k < 4; k++) gam[k] += xa * Wva[k];
            if (w3) {
                const float cf = xa * ys16;
                const float* W16 = W + (a * 17 + 16) * 17;
#pragma unroll
                for (int o = 0; o < 17; o++) acc[o] += cf * W16[o];
                gam16 += xa * Wv[a * 17 + 16];
            }
        }
#pragma unroll
        for (int k = 0; k < 4; k++) {
            const int d = c0 + k;
            const float cf = nv0 * yvo[k][0] + nv1 * yvo[k][1] + nv2 * yvo[k][2];
            const float* Wp = W + (272 + d) * 17;
#pragma unroll
            for (int o = 0; o < 17; o++) acc[o] += cf * Wp[o];
        }
        if (w3) {
            const float cf = nv0 * yv16[0] + nv1 * yv16[1] + nv2 * yv16[2];
            const float* Wp = W + (272 + 16) * 17;
#pragma unroll
            for (int o = 0; o < 17; o++) acc[o] += cf * Wp[o];
        }
        float vl0 = 0.f, vl1 = 0.f, vl2 = 0.f, sc2 = 0.f;
#pragma unroll
        for (int k = 0; k < 4; k++) {
            vl0 += gam[k] * yvo[k][0]; vl1 += gam[k] * yvo[k][1]; vl2 += gam[k] * yvo[k][2];
            sc2 += yso[k] * Wv[272 + c0 + k];
        }
        if (w3) {
            vl0 += gam16 * yv16[0]; vl1 += gam16 * yv16[1]; vl2 += gam16 * yv16[2];
            sc2 += ys16 * Wv[272 + 16];
        }
#pragma unroll
        for (int o = 0; o < 17; o++) part[o * 256 + tid] = acc[o];
        part[17 * 256 + tid] = vl0;
        part[18 * 256 + tid] = vl1;
        part[19 * 256 + tid] = vl2;
        part[20 * 256 + tid] = sc2;
        __syncthreads();
        float tot[21];
#pragma unroll
        for (int t = 0; t < 21; t++)
            tot[t] = part[t * 256 + lane] + part[t * 256 + 64 + lane] +
                     part[t * 256 + 128 + lane] + part[t * 256 + 192 + lane];
        const float g = sigm(tot[0]);
#pragma unroll
        for (int a = 0; a < 16; a++) nsreg[a] = gelu(tot[1 + a]);
        const float nx = (tot[17] + tot[20] * nv0) * g;
        const float ny = (tot[18] + tot[20] * nv1) * g;
        const float nz = (tot[19] + tot[20] * nv2) * g;
        nv0 = nx; nv1 = ny; nv2 = nz;
        if (b == 0 && w == 0) {
            float* p = nsl + lane * 17;
#pragma unroll
            for (int a = 0; a < 16; a++) p[a] = nsreg[a];
        }
        __syncthreads();
    }
    float so[16];
#pragma unroll
    for (int a = 0; a < 16; a++) so[a] = fbs[a];
#pragma unroll
    for (int p = 0; p < 16; p++) {
        const float x = nsreg[p];
#pragma unroll
        for (int a = 0; a < 16; a++) so[a] += x * lf[p * 16 + a];
    }
    if (valid && w == 0) {
        const float fw = fWv[0];
        float sn[16];
#pragma unroll
        for (int a = 0; a < 16; a++) { sn[a] = s[n * 16 + a] + so[a]; }
#pragma unroll
        for (int a = 0; a < 16; a++) s[n * 16 + a] = sn[a];
        const float w0o = nvv.x + nv0 * fw;
        const float w1o = nvv.y + nv1 * fw;
        const float w2o = nvv.z + nv2 * fw;
        v4[n] = make_float4(w0o, w1o, w2o, 0.f);
        if (out) {
#pragma unroll
            for (int a = 0; a < 16; a++) out[n * 19 + a] = sn[a];
            out[n * 19 + 16] = w0o;
            out[n * 19 + 17] = w1o;
            out[n * 19 + 18] = w2o;
        }
    }
}

extern "C" void kernel_launch(void* const* d_in, const int* in_sizes, int n_in,
                              void* d_out, int out_size, void* d_ws, size_t ws_size,
                              hipStream_t stream) {
    const float* node_scalars = (const float*)d_in[0];
    const float* node_pos = (const float*)d_in[1];
    const int* senders = (const int*)d_in[2];
    const int* receivers = (const int*)d_in[3];
    const float* eWs0 = (const float*)d_in[4];
    const float* ebs0 = (const float*)d_in[5];
    const float* eWv0 = (const float*)d_in[6];
    const float* eWs1 = (const float*)d_in[7];
    const float* ebs1 = (const float*)d_in[8];
    const float* eWv1 = (const float*)d_in[9];
    const float* nWs = (const float*)d_in[10];
    const float* nbs = (const float*)d_in[11];
    const float* nWv = (const float*)d_in[12];
    const float* fWs = (const float*)d_in[13];
    const float* fbs = (const float*)d_in[14];
    const float* fWv = (const float*)d_in[15];

    float* ws = (float*)d_ws;
    float* s = ws;                        // N*16
    float* v = s + N_NODES * 16;          // N*4 (float4)
    float* agg = v + N_NODES * 4;         // N*CH
    float* cnt = agg + N_NODES * CH;      // N
    int* offs = (int*)(cnt + N_NODES);    // N
    int* cursor = offs + N_NODES;         // N
    int* perm = cursor + N_NODES;         // E
    float* msg = (float*)(perm + N_EDGES);// E*CH (87 MB)
    float* out = (float*)d_out;
    float4* v4 = (float4*)v;

    init_kernel<<<(N_NODES * 16 + 255) / 256, 256, 0, stream>>>(node_scalars, node_pos, s, v4, cnt);
    count_kernel<<<(N_EDGES + 255) / 256, 256, 0, stream>>>(receivers, cnt);
    scan_kernel<<<1, 1024, 0, stream>>>(cnt, offs, cursor);
    scatter_kernel<<<(N_EDGES + 255) / 256, 256, 0, stream>>>(receivers, offs, cursor, perm);
    for (int t = 0; t < 3; t++) {
        edge_compute_kernel<<<N_EDGES / 512, 256, 0, stream>>>(
            (const float4*)s, (const float4*)v4, senders, receivers, perm,
            eWs0 + t * 34 * 32, ebs0 + t * 32, eWv0 + t * 34 * 16,
            eWs1 + t * 32 * 32, ebs1 + t * 32, eWv1 + t * 32 * 16,
            msg);
        agg_kernel<<<(N_NODES * CH + 255) / 256, 256, 0, stream>>>(msg, cnt, offs, agg);
        node_kernel<<<(N_NODES + 63) / 64, 256, 0, stream>>>(
            s, v4, agg, cnt,
            nWs + t * 2 * 289 * 17, nbs + t * 2 * 17, nWv + t * 2 * 289,
            fWs + t * 256, fbs + t * 16, fWv + t,
            (t == 2) ? out : nullptr);
    }
}

// Round 8
// 716.401 us; speedup vs baseline: 1.2841x; 1.2841x over previous
//
#include <hip/hip_runtime.h>

#define N_NODES 20000
#define N_EDGES 320000
#define CH 68

__device__ __forceinline__ float sigm(float x) { return 1.0f / (1.0f + __expf(-x)); }
// jax.nn.gelu approximate=True == x*sigmoid(1.5957691*(x+0.044715x^3))
__device__ __forceinline__ float gelu(float x) {
    return x * sigm(1.5957691216057308f * (x + 0.044715f * x * x * x));
}

__global__ void init_kernel(const float* __restrict__ s0, const float* __restrict__ p0,
                            float* __restrict__ s, float4* __restrict__ v4,
                            float* __restrict__ cnt) {
    int idx = blockIdx.x * 256 + threadIdx.x;
    if (idx < N_NODES * 16) s[idx] = s0[idx];
    if (idx < N_NODES) {
        v4[idx] = make_float4(p0[idx * 3], p0[idx * 3 + 1], p0[idx * 3 + 2], 0.f);
        cnt[idx] = 0.f;
    }
}

__global__ void count_kernel(const int* __restrict__ rcv, float* __restrict__ cnt) {
    int e = blockIdx.x * 256 + threadIdx.x;
    if (e < N_EDGES) unsafeAtomicAdd(&cnt[rcv[e]], 1.0f);
}

// one-block exclusive scan of cnt -> offs; zero the scatter cursors.
__global__ __launch_bounds__(1024) void scan_kernel(const float* __restrict__ cnt,
                                                    int* __restrict__ offs,
                                                    int* __restrict__ cursor) {
    __shared__ int sdata[1024];
    const int t = threadIdx.x;
    const int base = t * 20;  // 1024*20 = 20480 >= N_NODES
    int local[20];
    int sum = 0;
#pragma unroll
    for (int k = 0; k < 20; k++) {
        const int n = base + k;
        const int c = (n < N_NODES) ? (int)cnt[n] : 0;
        local[k] = sum;
        sum += c;
    }
    sdata[t] = sum;
    __syncthreads();
    for (int d = 1; d < 1024; d <<= 1) {
        const int v = (t >= d) ? sdata[t - d] : 0;
        __syncthreads();
        sdata[t] += v;
        __syncthreads();
    }
    const int pre = (t == 0) ? 0 : sdata[t - 1];
#pragma unroll
    for (int k = 0; k < 20; k++) {
        const int n = base + k;
        if (n < N_NODES) {
            offs[n] = pre + local[k];
            cursor[n] = 0;
        }
    }
}

// receiver-sorted permutation: perm[slot] = original edge id
__global__ void scatter_kernel(const int* __restrict__ rcv, const int* __restrict__ offs,
                               int* __restrict__ cursor, int* __restrict__ perm) {
    int e = blockIdx.x * 256 + threadIdx.x;
    if (e < N_EDGES) {
        const int n = rcv[e];
        const int slot = offs[n] + atomicAdd(&cursor[n], 1);
        perm[slot] = e;
    }
}

// Edge compute: weights in LDS, E=2 edges/thread, ONE-WAVE blocks.
// R7 lesson: E=2 under launch_bounds(256,2) got VGPR capped at 128 vs a ~240
// live set -> scratch spills (FETCH 37->198 MB, WRITE 121->327 MB) ate the win.
// The VGPR budget is per-wave-per-SIMD: a 64-thread (1-wave) block with
// launch_bounds(64,1) lets the allocator take ~240 regs spill-free (HW allows
// ~450 at 1 wave/SIMD). VGPR ~240 -> 2 waves/SIMD resident (same residency as
// R6) but each wave's 792 ds_read_b128 broadcast stream now feeds 128 edges:
// per-CU LDS pipe 186k -> 93k cy; VALU (~156k cy = 65 us) becomes the floor.
// LDS layout: [0:1088) Ws0, [1088:1632) Wv0, [1632:2656) Ws1, [2656:3168) Wv1.
__global__ __launch_bounds__(64, 1) void edge_compute_kernel(
    const float4* __restrict__ s4, const float4* __restrict__ v4,
    const int* __restrict__ snd, const int* __restrict__ rcv,
    const int* __restrict__ perm,
    const float* __restrict__ Ws0, const float* __restrict__ bs0, const float* __restrict__ Wv0,
    const float* __restrict__ Ws1, const float* __restrict__ bs1, const float* __restrict__ Wv1,
    float* __restrict__ msg) {
    __shared__ float lW[3168];
    const int tid = threadIdx.x;
    {
        // float4 staging (all four blocks are 16B-aligned)
        float4* d = (float4*)lW;
        const float4* a = (const float4*)Ws0;
        const float4* b = (const float4*)Wv0;
        const float4* c = (const float4*)Ws1;
        const float4* e4 = (const float4*)Wv1;
        for (int idx = tid; idx < 272; idx += 64) d[idx] = a[idx];
        for (int idx = tid; idx < 136; idx += 64) d[272 + idx] = b[idx];
        for (int idx = tid; idx < 256; idx += 64) d[408 + idx] = c[idx];
        for (int idx = tid; idx < 128; idx += 64) d[664 + idx] = e4[idx];
    }
    __syncthreads();
    const float* __restrict__ lWs0 = lW;
    const float* __restrict__ lWv0 = lW + 1088;
    const float* __restrict__ lWs1 = lW + 1632;
    const float* __restrict__ lWv1 = lW + 2656;

    const int eA = blockIdx.x * 128 + tid;  // grid = 2500 covers N_EDGES exactly
    const int eB = eA + 64;
    const int eidA = perm[eA], eidB = perm[eB];
    const int iA = snd[eidA], jA = rcv[eidA];
    const int iB = snd[eidB], jB = rcv[eidB];

    const float4 viA4 = v4[iA], vjA4 = v4[jA];
    const float4 viB4 = v4[iB], vjB4 = v4[jB];
    const float vi0A = viA4.x, vi1A = viA4.y, vi2A = viA4.z;
    const float vj0A = vjA4.x, vj1A = vjA4.y, vj2A = vjA4.z;
    const float vi0B = viB4.x, vi1B = viB4.y, vi2B = viB4.z;
    const float vj0B = vjB4.x, vj1B = vjB4.y, vj2B = vjB4.z;
    float a0A, a1A, a2A, a0B, a1B, a2B;
    {
        const float r0 = vi0A - vj0A, r1 = vi1A - vj1A, r2 = vi2A - vj2A;
        const float scl = 1.7320508075688772f / (sqrtf(r0 * r0 + r1 * r1 + r2 * r2) + 1e-8f);
        a0A = r0 * scl; a1A = r1 * scl; a2A = r2 * scl;
    }
    {
        const float r0 = vi0B - vj0B, r1 = vi1B - vj1B, r2 = vi2B - vj2B;
        const float scl = 1.7320508075688772f / (sqrtf(r0 * r0 + r1 * r1 + r2 * r2) + 1e-8f);
        a0B = r0 * scl; a1B = r1 * scl; a2B = r2 * scl;
    }

    float xsA[32], xsB[32];
    {
        float4 A = s4[iA * 4 + 0], B = s4[iA * 4 + 1], C = s4[iA * 4 + 2], D = s4[iA * 4 + 3];
        xsA[0] = A.x; xsA[1] = A.y; xsA[2] = A.z; xsA[3] = A.w;
        xsA[4] = B.x; xsA[5] = B.y; xsA[6] = B.z; xsA[7] = B.w;
        xsA[8] = C.x; xsA[9] = C.y; xsA[10] = C.z; xsA[11] = C.w;
        xsA[12] = D.x; xsA[13] = D.y; xsA[14] = D.z; xsA[15] = D.w;
        A = s4[jA * 4 + 0]; B = s4[jA * 4 + 1]; C = s4[jA * 4 + 2]; D = s4[jA * 4 + 3];
        xsA[16] = A.x; xsA[17] = A.y; xsA[18] = A.z; xsA[19] = A.w;
        xsA[20] = B.x; xsA[21] = B.y; xsA[22] = B.z; xsA[23] = B.w;
        xsA[24] = C.x; xsA[25] = C.y; xsA[26] = C.z; xsA[27] = C.w;
        xsA[28] = D.x; xsA[29] = D.y; xsA[30] = D.z; xsA[31] = D.w;
        A = s4[iB * 4 + 0]; B = s4[iB * 4 + 1]; C = s4[iB * 4 + 2]; D = s4[iB * 4 + 3];
        xsB[0] = A.x; xsB[1] = A.y; xsB[2] = A.z; xsB[3] = A.w;
        xsB[4] = B.x; xsB[5] = B.y; xsB[6] = B.z; xsB[7] = B.w;
        xsB[8] = C.x; xsB[9] = C.y; xsB[10] = C.z; xsB[11] = C.w;
        xsB[12] = D.x; xsB[13] = D.y; xsB[14] = D.z; xsB[15] = D.w;
        A = s4[jB * 4 + 0]; B = s4[jB * 4 + 1]; C = s4[jB * 4 + 2]; D = s4[jB * 4 + 3];
        xsB[16] = A.x; xsB[17] = A.y; xsB[18] = A.z; xsB[19] = A.w;
        xsB[20] = B.x; xsB[21] = B.y; xsB[22] = B.z; xsB[23] = B.w;
        xsB[24] = C.x; xsB[25] = C.y; xsB[26] = C.z; xsB[27] = C.w;
        xsB[28] = D.x; xsB[29] = D.y; xsB[30] = D.z; xsB[31] = D.w;
    }
    const float diA = vi0A * a0A + vi1A * a1A + vi2A * a2A;
    const float djA = vj0A * a0A + vj1A * a1A + vj2A * a2A;
    const float diB = vi0B * a0B + vi1B * a1B + vi2B * a2B;
    const float djB = vj0B * a0B + vj1B * a1B + vj2B * a2B;

    // ---- TPLG 0 ----
    float slA[32], slB[32];
#pragma unroll
    for (int o = 0; o < 32; o++) {
        const float b = bs0[o], w32 = lWs0[1024 + o], w33 = lWs0[1056 + o];
        slA[o] = b + diA * w32 + djA * w33;
        slB[o] = b + diB * w32 + djB * w33;
    }
#pragma unroll
    for (int p = 0; p < 32; p++) {
        const float xA = xsA[p], xB = xsB[p];
#pragma unroll
        for (int o = 0; o < 32; o++) {
            const float w = lWs0[p * 32 + o];
            slA[o] += xA * w; slB[o] += xB * w;
        }
    }
    float alA[16], alB[16];
#pragma unroll
    for (int q = 0; q < 16; q++) { alA[q] = 0.f; alB[q] = 0.f; }
#pragma unroll
    for (int p = 0; p < 32; p++) {
        const float xA = xsA[p], xB = xsB[p];
#pragma unroll
        for (int q = 0; q < 16; q++) {
            const float w = lWv0[p * 16 + q];
            alA[q] += xA * w; alB[q] += xB * w;
        }
    }
    float msA[16], mv0A[16], mv1A[16], mv2A[16];
    float msB[16], mv0B[16], mv1B[16], mv2B[16];
#pragma unroll
    for (int q = 0; q < 16; q++) {
        const float w32 = lWv0[512 + q], w33 = lWv0[528 + q];
        const float gA = sigm(slA[q]);
        mv0A[q] = (alA[q] * a0A + w32 * vi0A + w33 * vj0A) * gA;
        mv1A[q] = (alA[q] * a1A + w32 * vi1A + w33 * vj1A) * gA;
        mv2A[q] = (alA[q] * a2A + w32 * vi2A + w33 * vj2A) * gA;
        const float gB = sigm(slB[q]);
        mv0B[q] = (alB[q] * a0B + w32 * vi0B + w33 * vj0B) * gB;
        mv1B[q] = (alB[q] * a1B + w32 * vi1B + w33 * vj1B) * gB;
        mv2B[q] = (alB[q] * a2B + w32 * vi2B + w33 * vj2B) * gB;
    }
#pragma unroll
    for (int p = 0; p < 16; p++) { msA[p] = gelu(slA[16 + p]); msB[p] = gelu(slB[16 + p]); }

    // ---- TPLG 1 ----
    float sl2A[32], sl2B[32];
#pragma unroll
    for (int o = 0; o < 32; o++) { const float b = bs1[o]; sl2A[o] = b; sl2B[o] = b; }
#pragma unroll
    for (int p = 0; p < 16; p++) {
        const float xA = msA[p], xB = msB[p];
#pragma unroll
        for (int o = 0; o < 32; o++) {
            const float w = lWs1[p * 32 + o];
            sl2A[o] += xA * w; sl2B[o] += xB * w;
        }
    }
#pragma unroll
    for (int q = 0; q < 16; q++) {
        const float xA = mv0A[q] * a0A + mv1A[q] * a1A + mv2A[q] * a2A;
        const float xB = mv0B[q] * a0B + mv1B[q] * a1B + mv2B[q] * a2B;
#pragma unroll
        for (int o = 0; o < 32; o++) {
            const float w = lWs1[(16 + q) * 32 + o];
            sl2A[o] += xA * w; sl2B[o] += xB * w;
        }
    }

    // ---- stream message rows; scalars first (frees sl2[16..31]) ----
    float4* mrowA = (float4*)(msg + (size_t)eA * CH);
    float4* mrowB = (float4*)(msg + (size_t)eB * CH);
    mrowA[0] = make_float4(gelu(sl2A[16]), gelu(sl2A[17]), gelu(sl2A[18]), gelu(sl2A[19]));
    mrowA[1] = make_float4(gelu(sl2A[20]), gelu(sl2A[21]), gelu(sl2A[22]), gelu(sl2A[23]));
    mrowA[2] = make_float4(gelu(sl2A[24]), gelu(sl2A[25]), gelu(sl2A[26]), gelu(sl2A[27]));
    mrowA[3] = make_float4(gelu(sl2A[28]), gelu(sl2A[29]), gelu(sl2A[30]), gelu(sl2A[31]));
    mrowB[0] = make_float4(gelu(sl2B[16]), gelu(sl2B[17]), gelu(sl2B[18]), gelu(sl2B[19]));
    mrowB[1] = make_float4(gelu(sl2B[20]), gelu(sl2B[21]), gelu(sl2B[22]), gelu(sl2B[23]));
    mrowB[2] = make_float4(gelu(sl2B[24]), gelu(sl2B[25]), gelu(sl2B[26]), gelu(sl2B[27]));
    mrowB[3] = make_float4(gelu(sl2B[28]), gelu(sl2B[29]), gelu(sl2B[30]), gelu(sl2B[31]));
#pragma unroll
    for (int qg = 0; qg < 4; qg++) {
        float tA[12], tB[12];
#pragma unroll
        for (int qq = 0; qq < 4; qq++) {
            const int q = qg * 4 + qq;
            float beA = 0.f, beB = 0.f;
#pragma unroll
            for (int p = 0; p < 16; p++) {
                const float w = lWv1[p * 16 + q];
                beA += msA[p] * w; beB += msB[p] * w;
            }
            float u0A = beA * a0A, u1A = beA * a1A, u2A = beA * a2A;
            float u0B = beB * a0B, u1B = beB * a1B, u2B = beB * a2B;
#pragma unroll
            for (int p = 0; p < 16; p++) {
                const float w = lWv1[(16 + p) * 16 + q];
                u0A += mv0A[p] * w; u1A += mv1A[p] * w; u2A += mv2A[p] * w;
                u0B += mv0B[p] * w; u1B += mv1B[p] * w; u2B += mv2B[p] * w;
            }
            const float gA = sigm(sl2A[q]), gB = sigm(sl2B[q]);
            tA[qq * 3 + 0] = u0A * gA; tA[qq * 3 + 1] = u1A * gA; tA[qq * 3 + 2] = u2A * gA;
            tB[qq * 3 + 0] = u0B * gB; tB[qq * 3 + 1] = u1B * gB; tB[qq * 3 + 2] = u2B * gB;
        }
        mrowA[4 + qg * 3 + 0] = make_float4(tA[0], tA[1], tA[2], tA[3]);
        mrowA[4 + qg * 3 + 1] = make_float4(tA[4], tA[5], tA[6], tA[7]);
        mrowA[4 + qg * 3 + 2] = make_float4(tA[8], tA[9], tA[10], tA[11]);
        mrowB[4 + qg * 3 + 0] = make_float4(tB[0], tB[1], tB[2], tB[3]);
        mrowB[4 + qg * 3 + 1] = make_float4(tB[4], tB[5], tB[6], tB[7]);
        mrowB[4 + qg * 3 + 2] = make_float4(tB[8], tB[9], tB[10], tB[11]);
    }
    mrowA[16] = make_float4(a0A, a1A, a2A, 0.f);
    mrowB[16] = make_float4(a0B, a1B, a2B, 0.f);
}

// Gather-aggregate: node n's messages are rows offs[n]..offs[n]+cnt[n]-1,
// contiguous (receiver-sorted). One thread per (node, channel). No atomics.
__global__ __launch_bounds__(256) void agg_kernel(const float* __restrict__ msg,
                                                  const float* __restrict__ cnt,
                                                  const int* __restrict__ offs,
                                                  float* __restrict__ agg) {
    const int id = blockIdx.x * 256 + threadIdx.x;
    if (id >= N_NODES * CH) return;
    const int n = id / CH;
    const int c = id - n * CH;
    const int deg = (int)cnt[n];
    const float* p = msg + (size_t)offs[n] * CH + c;
    float acc = 0.f;
    int r = 0;
    for (; r + 4 <= deg; r += 4) {
        acc += p[(size_t)(r + 0) * CH] + p[(size_t)(r + 1) * CH] +
               p[(size_t)(r + 2) * CH] + p[(size_t)(r + 3) * CH];
    }
    for (; r < deg; r++) acc += p[(size_t)r * CH];
    agg[id] = acc;
}

// 256 threads = 4 waves; block handles 64 nodes; wave w owns channel slice c/d in [4w,4w+4) (+16 on w3).
__global__ __launch_bounds__(256, 2) void node_kernel(
    float* __restrict__ s, float4* __restrict__ v4,
    float* __restrict__ agg, const float* __restrict__ cntb,
    const float* __restrict__ nWs, const float* __restrict__ nbs, const float* __restrict__ nWv,
    const float* __restrict__ fWs, const float* __restrict__ fbs, const float* __restrict__ fWv,
    float* __restrict__ out) {
    __shared__ float nsl[64 * 17];       // per-node ns, stride 17 (conflict-free)
    __shared__ float part[21 * 256];     // partials: [t][w][lane]
    __shared__ float lw[289 * 17 + 289]; // current b: Ws then Wv (20.8 KB)
    __shared__ float lf[256];            // fWs
    const int tid = threadIdx.x;
    const int lane = tid & 63;
    const int w = tid >> 6;
    const int n0 = blockIdx.x * 64 + lane;
    const bool valid = n0 < N_NODES;
    const int n = valid ? n0 : 0;
    const float inv = 1.0f / 319999.0f;  // 1/(E-1)
    const float cnt = cntb[n];
    const float f = inv / fmaxf(cnt, 1.0f);
    float* ag = agg + n * CH;
    const int c0 = w * 4;
    const bool w3 = (w == 3);

    if (tid < 256) lf[tid] = fWs[tid];

    float yso[4];
#pragma unroll
    for (int k = 0; k < 4; k++) yso[k] = ag[c0 + k] * f;
    const float ys16 = cnt * f;
    float yvo[4][3];
#pragma unroll
    for (int k = 0; k < 4; k++) {
        const int d = c0 + k;
        yvo[k][0] = ag[16 + d * 3 + 0] * f;
        yvo[k][1] = ag[16 + d * 3 + 1] * f;
        yvo[k][2] = ag[16 + d * 3 + 2] * f;
    }
    float yv16[3] = {ag[64] * f, ag[65] * f, ag[66] * f};
    const float4 nvv = v4[n];
    float nv0 = nvv.x, nv1 = nvv.y, nv2 = nvv.z;

    if (w == 0) {
        const float4* srow = (const float4*)(s + n * 16);
        const float4 A = srow[0], B = srow[1], C = srow[2], D = srow[3];
        float* p = nsl + lane * 17;
        p[0] = A.x; p[1] = A.y; p[2] = A.z; p[3] = A.w;
        p[4] = B.x; p[5] = B.y; p[6] = B.z; p[7] = B.w;
        p[8] = C.x; p[9] = C.y; p[10] = C.z; p[11] = C.w;
        p[12] = D.x; p[13] = D.y; p[14] = D.z; p[15] = D.w;
    }

    float nsreg[16];
#pragma unroll 1
    for (int b = 0; b < 2; b++) {
        for (int idx = tid; idx < 289 * 17; idx += 256) lw[idx] = nWs[b * 289 * 17 + idx];
        for (int idx = tid; idx < 289; idx += 256) lw[289 * 17 + idx] = nWv[b * 289 + idx];
        __syncthreads();
        const float* W = lw;
        const float* Wv = lw + 289 * 17;
        const float* bb = nbs + b * 17;
        float acc[17];
#pragma unroll
        for (int o = 0; o < 17; o++) acc[o] = (w == 0) ? bb[o] : 0.f;
        float gam[4] = {0.f, 0.f, 0.f, 0.f};
        float gam16 = 0.f;
#pragma unroll 2
        for (int a = 0; a < 16; a++) {
            const float xa = nsl[lane * 17 + a];
            const float* Wa = W + (a * 17 + c0) * 17;
#pragma unroll
            for (int k = 0; k < 4; k++) {
                const float cf = xa * yso[k];
#pragma unroll
                for (int o = 0; o < 17; o++) acc[o] += cf * Wa[k * 17 + o];
            }
            const float* Wva = Wv + a * 17 + c0;
#pragma unroll
            for (int k = 0; k < 4; k++) gam[k] += xa * Wva[k];
            if (w3) {
                const float cf = xa * ys16;
                const float* W16 = W + (a * 17 + 16) * 17;
#pragma unroll
                for (int o = 0; o < 17; o++) acc[o] += cf * W16[o];
                gam16 += xa * Wv[a * 17 + 16];
            }
        }
#pragma unroll
        for (int k = 0; k < 4; k++) {
            const int d = c0 + k;
            const float cf = nv0 * yvo[k][0] + nv1 * yvo[k][1] + nv2 * yvo[k][2];
            const float* Wp = W + (272 + d) * 17;
#pragma unroll
            for (int o = 0; o < 17; o++) acc[o] += cf * Wp[o];
        }
        if (w3) {
            const float cf = nv0 * yv16[0] + nv1 * yv16[1] + nv2 * yv16[2];
            const float* Wp = W + (272 + 16) * 17;
#pragma unroll
            for (int o = 0; o < 17; o++) acc[o] += cf * Wp[o];
        }
        float vl0 = 0.f, vl1 = 0.f, vl2 = 0.f, sc2 = 0.f;
#pragma unroll
        for (int k = 0; k < 4; k++) {
            vl0 += gam[k] * yvo[k][0]; vl1 += gam[k] * yvo[k][1]; vl2 += gam[k] * yvo[k][2];
            sc2 += yso[k] * Wv[272 + c0 + k];
        }
        if (w3) {
            vl0 += gam16 * yv16[0]; vl1 += gam16 * yv16[1]; vl2 += gam16 * yv16[2];
            sc2 += ys16 * Wv[272 + 16];
        }
#pragma unroll
        for (int o = 0; o < 17; o++) part[o * 256 + tid] = acc[o];
        part[17 * 256 + tid] = vl0;
        part[18 * 256 + tid] = vl1;
        part[19 * 256 + tid] = vl2;
        part[20 * 256 + tid] = sc2;
        __syncthreads();
        float tot[21];
#pragma unroll
        for (int t = 0; t < 21; t++)
            tot[t] = part[t * 256 + lane] + part[t * 256 + 64 + lane] +
                     part[t * 256 + 128 + lane] + part[t * 256 + 192 + lane];
        const float g = sigm(tot[0]);
#pragma unroll
        for (int a = 0; a < 16; a++) nsreg[a] = gelu(tot[1 + a]);
        const float nx = (tot[17] + tot[20] * nv0) * g;
        const float ny = (tot[18] + tot[20] * nv1) * g;
        const float nz = (tot[19] + tot[20] * nv2) * g;
        nv0 = nx; nv1 = ny; nv2 = nz;
        if (b == 0 && w == 0) {
            float* p = nsl + lane * 17;
#pragma unroll
            for (int a = 0; a < 16; a++) p[a] = nsreg[a];
        }
        __syncthreads();
    }
    float so[16];
#pragma unroll
    for (int a = 0; a < 16; a++) so[a] = fbs[a];
#pragma unroll
    for (int p = 0; p < 16; p++) {
        const float x = nsreg[p];
#pragma unroll
        for (int a = 0; a < 16; a++) so[a] += x * lf[p * 16 + a];
    }
    if (valid && w == 0) {
        const float fw = fWv[0];
        float sn[16];
#pragma unroll
        for (int a = 0; a < 16; a++) { sn[a] = s[n * 16 + a] + so[a]; }
#pragma unroll
        for (int a = 0; a < 16; a++) s[n * 16 + a] = sn[a];
        const float w0o = nvv.x + nv0 * fw;
        const float w1o = nvv.y + nv1 * fw;
        const float w2o = nvv.z + nv2 * fw;
        v4[n] = make_float4(w0o, w1o, w2o, 0.f);
        if (out) {
#pragma unroll
            for (int a = 0; a < 16; a++) out[n * 19 + a] = sn[a];
            out[n * 19 + 16] = w0o;
            out[n * 19 + 17] = w1o;
            out[n * 19 + 18] = w2o;
        }
    }
}

extern "C" void kernel_launch(void* const* d_in, const int* in_sizes, int n_in,
                              void* d_out, int out_size, void* d_ws, size_t ws_size,
                              hipStream_t stream) {
    const float* node_scalars = (const float*)d_in[0];
    const float* node_pos = (const float*)d_in[1];
    const int* senders = (const int*)d_in[2];
    const int* receivers = (const int*)d_in[3];
    const float* eWs0 = (const float*)d_in[4];
    const float* ebs0 = (const float*)d_in[5];
    const float* eWv0 = (const float*)d_in[6];
    const float* eWs1 = (const float*)d_in[7];
    const float* ebs1 = (const float*)d_in[8];
    const float* eWv1 = (const float*)d_in[9];
    const float* nWs = (const float*)d_in[10];
    const float* nbs = (const float*)d_in[11];
    const float* nWv = (const float*)d_in[12];
    const float* fWs = (const float*)d_in[13];
    const float* fbs = (const float*)d_in[14];
    const float* fWv = (const float*)d_in[15];

    float* ws = (float*)d_ws;
    float* s = ws;                        // N*16
    float* v = s + N_NODES * 16;          // N*4 (float4)
    float* agg = v + N_NODES * 4;         // N*CH
    float* cnt = agg + N_NODES * CH;      // N
    int* offs = (int*)(cnt + N_NODES);    // N
    int* cursor = offs + N_NODES;         // N
    int* perm = cursor + N_NODES;         // E
    float* msg = (float*)(perm + N_EDGES);// E*CH (87 MB)
    float* out = (float*)d_out;
    float4* v4 = (float4*)v;

    init_kernel<<<(N_NODES * 16 + 255) / 256, 256, 0, stream>>>(node_scalars, node_pos, s, v4, cnt);
    count_kernel<<<(N_EDGES + 255) / 256, 256, 0, stream>>>(receivers, cnt);
    scan_kernel<<<1, 1024, 0, stream>>>(cnt, offs, cursor);
    scatter_kernel<<<(N_EDGES + 255) / 256, 256, 0, stream>>>(receivers, offs, cursor, perm);
    for (int t = 0; t < 3; t++) {
        edge_compute_kernel<<<N_EDGES / 128, 64, 0, stream>>>(
            (const float4*)s, (const float4*)v4, senders, receivers, perm,
            eWs0 + t * 34 * 32, ebs0 + t * 32, eWv0 + t * 34 * 16,
            eWs1 + t * 32 * 32, ebs1 + t * 32, eWv1 + t * 32 * 16,
            msg);
        agg_kernel<<<(N_NODES * CH + 255) / 256, 256, 0, stream>>>(msg, cnt, offs, agg);
        node_kernel<<<(N_NODES + 63) / 64, 256, 0, stream>>>(
            s, v4, agg, cnt,
            nWs + t * 2 * 289 * 17, nbs + t * 2 * 17, nWv + t * 2 * 289,
            fWs + t * 256, fbs + t * 16, fWv + t,
            (t == 2) ? out : nullptr);
    }
}

// Round 9
// 580.085 us; speedup vs baseline: 1.5859x; 1.2350x over previous
//
#include <hip/hip_runtime.h>

#define N_NODES 20000
#define N_EDGES 320000
#define CH 68

__device__ __forceinline__ float sigm(float x) { return 1.0f / (1.0f + __expf(-x)); }
// jax.nn.gelu approximate=True == x*sigmoid(1.5957691*(x+0.044715x^3))
__device__ __forceinline__ float gelu(float x) {
    return x * sigm(1.5957691216057308f * (x + 0.044715f * x * x * x));
}

__global__ void init_kernel(const float* __restrict__ s0, const float* __restrict__ p0,
                            float* __restrict__ s, float4* __restrict__ v4,
                            float* __restrict__ cnt) {
    int idx = blockIdx.x * 256 + threadIdx.x;
    if (idx < N_NODES * 16) s[idx] = s0[idx];
    if (idx < N_NODES) {
        v4[idx] = make_float4(p0[idx * 3], p0[idx * 3 + 1], p0[idx * 3 + 2], 0.f);
        cnt[idx] = 0.f;
    }
}

__global__ void count_kernel(const int* __restrict__ rcv, float* __restrict__ cnt) {
    int e = blockIdx.x * 256 + threadIdx.x;
    if (e < N_EDGES) unsafeAtomicAdd(&cnt[rcv[e]], 1.0f);
}

// one-block exclusive scan of cnt -> offs; zero the scatter cursors.
__global__ __launch_bounds__(1024) void scan_kernel(const float* __restrict__ cnt,
                                                    int* __restrict__ offs,
                                                    int* __restrict__ cursor) {
    __shared__ int sdata[1024];
    const int t = threadIdx.x;
    const int base = t * 20;  // 1024*20 = 20480 >= N_NODES
    int local[20];
    int sum = 0;
#pragma unroll
    for (int k = 0; k < 20; k++) {
        const int n = base + k;
        const int c = (n < N_NODES) ? (int)cnt[n] : 0;
        local[k] = sum;
        sum += c;
    }
    sdata[t] = sum;
    __syncthreads();
    for (int d = 1; d < 1024; d <<= 1) {
        const int v = (t >= d) ? sdata[t - d] : 0;
        __syncthreads();
        sdata[t] += v;
        __syncthreads();
    }
    const int pre = (t == 0) ? 0 : sdata[t - 1];
#pragma unroll
    for (int k = 0; k < 20; k++) {
        const int n = base + k;
        if (n < N_NODES) {
            offs[n] = pre + local[k];
            cursor[n] = 0;
        }
    }
}

// receiver-sorted permutation: perm[slot] = original edge id
__global__ void scatter_kernel(const int* __restrict__ rcv, const int* __restrict__ offs,
                               int* __restrict__ cursor, int* __restrict__ perm) {
    int e = blockIdx.x * 256 + threadIdx.x;
    if (e < N_EDGES) {
        const int n = rcv[e];
        const int slot = offs[n] + atomicAdd(&cursor[n], 1);
        perm[slot] = e;
    }
}

// Edge compute, weights in LDS (R6-exact: measured 111 us, VGPR 124, the
// calibrated optimum of this family: LDS broadcast pipe ~77 us + VALU ~73 us
// overlapping). E=2 variants falsified twice: 256-thr blocks spill at the
// 128-VGPR cap (R7), 1-wave blocks starve residency (R8, 3 waves/CU).
// LDS layout: [0:1088) Ws0, [1088:1632) Wv0, [1632:2656) Ws1, [2656:3168) Wv1.
__global__ __launch_bounds__(256) void edge_compute_kernel(
    const float4* __restrict__ s4, const float4* __restrict__ v4,
    const int* __restrict__ snd, const int* __restrict__ rcv,
    const int* __restrict__ perm,
    const float* __restrict__ Ws0, const float* __restrict__ bs0, const float* __restrict__ Wv0,
    const float* __restrict__ Ws1, const float* __restrict__ bs1, const float* __restrict__ Wv1,
    float* __restrict__ msg) {
    __shared__ float lW[3168];
    const int tid = threadIdx.x;
    {
        for (int idx = tid; idx < 1088; idx += 256) lW[idx] = Ws0[idx];
        for (int idx = tid; idx < 544; idx += 256) lW[1088 + idx] = Wv0[idx];
        for (int idx = tid; idx < 1024; idx += 256) lW[1632 + idx] = Ws1[idx];
        for (int idx = tid; idx < 512; idx += 256) lW[2656 + idx] = Wv1[idx];
    }
    __syncthreads();
    const float* __restrict__ lWs0 = lW;
    const float* __restrict__ lWv0 = lW + 1088;
    const float* __restrict__ lWs1 = lW + 1632;
    const float* __restrict__ lWv1 = lW + 2656;

    const int e = blockIdx.x * 256 + tid;  // grid = 1250 covers N_EDGES exactly
    const int eid = perm[e];
    const int i = snd[eid], j = rcv[eid];

    const float4 vi4 = v4[i], vj4 = v4[j];
    const float vi0 = vi4.x, vi1 = vi4.y, vi2 = vi4.z;
    const float vj0 = vj4.x, vj1 = vj4.y, vj2 = vj4.z;
    const float r0 = vi0 - vj0, r1 = vi1 - vj1, r2 = vi2 - vj2;
    const float nrm = sqrtf(r0 * r0 + r1 * r1 + r2 * r2);
    const float scl = 1.7320508075688772f / (nrm + 1e-8f);  // sqrt(3) * rhat
    const float a0 = r0 * scl, a1 = r1 * scl, a2 = r2 * scl;

    float xs[32];
    {
        float4 A = s4[i * 4 + 0], B = s4[i * 4 + 1], C = s4[i * 4 + 2], D = s4[i * 4 + 3];
        xs[0] = A.x; xs[1] = A.y; xs[2] = A.z; xs[3] = A.w;
        xs[4] = B.x; xs[5] = B.y; xs[6] = B.z; xs[7] = B.w;
        xs[8] = C.x; xs[9] = C.y; xs[10] = C.z; xs[11] = C.w;
        xs[12] = D.x; xs[13] = D.y; xs[14] = D.z; xs[15] = D.w;
        A = s4[j * 4 + 0]; B = s4[j * 4 + 1]; C = s4[j * 4 + 2]; D = s4[j * 4 + 3];
        xs[16] = A.x; xs[17] = A.y; xs[18] = A.z; xs[19] = A.w;
        xs[20] = B.x; xs[21] = B.y; xs[22] = B.z; xs[23] = B.w;
        xs[24] = C.x; xs[25] = C.y; xs[26] = C.z; xs[27] = C.w;
        xs[28] = D.x; xs[29] = D.y; xs[30] = D.z; xs[31] = D.w;
    }
    const float di = vi0 * a0 + vi1 * a1 + vi2 * a2;
    const float dj = vj0 * a0 + vj1 * a1 + vj2 * a2;

    // ---- TPLG 0 ----
    float sl[32];
#pragma unroll
    for (int o = 0; o < 32; o++) sl[o] = bs0[o] + di * lWs0[32 * 32 + o] + dj * lWs0[33 * 32 + o];
#pragma unroll
    for (int p = 0; p < 32; p++) {
        const float x = xs[p];
#pragma unroll
        for (int o = 0; o < 32; o++) sl[o] += x * lWs0[p * 32 + o];
    }
    float al[16];
#pragma unroll
    for (int q = 0; q < 16; q++) al[q] = 0.f;
#pragma unroll
    for (int p = 0; p < 32; p++) {
        const float x = xs[p];
#pragma unroll
        for (int q = 0; q < 16; q++) al[q] += x * lWv0[p * 16 + q];
    }
    float ms[16], mv0[16], mv1[16], mv2[16];
#pragma unroll
    for (int q = 0; q < 16; q++) {
        const float g = sigm(sl[q]);
        const float w32 = lWv0[32 * 16 + q], w33 = lWv0[33 * 16 + q];
        mv0[q] = (al[q] * a0 + w32 * vi0 + w33 * vj0) * g;
        mv1[q] = (al[q] * a1 + w32 * vi1 + w33 * vj1) * g;
        mv2[q] = (al[q] * a2 + w32 * vi2 + w33 * vj2) * g;
    }
#pragma unroll
    for (int p = 0; p < 16; p++) ms[p] = gelu(sl[16 + p]);

    // ---- TPLG 1 ----
    float sl2[32];
#pragma unroll
    for (int o = 0; o < 32; o++) sl2[o] = bs1[o];
#pragma unroll
    for (int p = 0; p < 16; p++) {
        const float x = ms[p];
#pragma unroll
        for (int o = 0; o < 32; o++) sl2[o] += x * lWs1[p * 32 + o];
    }
#pragma unroll
    for (int q = 0; q < 16; q++) {
        const float x = mv0[q] * a0 + mv1[q] * a1 + mv2[q] * a2;
#pragma unroll
        for (int o = 0; o < 32; o++) sl2[o] += x * lWs1[(16 + q) * 32 + o];
    }

    // ---- stream the 68-float message row (float4-aligned: 68 = 17*4) ----
    // layout: [0..15]=scalars, [16..63]=mv q*3+r, [64..66]=a_v
    float4* mrow = (float4*)(msg + (size_t)e * CH);
    mrow[0] = make_float4(gelu(sl2[16]), gelu(sl2[17]), gelu(sl2[18]), gelu(sl2[19]));
    mrow[1] = make_float4(gelu(sl2[20]), gelu(sl2[21]), gelu(sl2[22]), gelu(sl2[23]));
    mrow[2] = make_float4(gelu(sl2[24]), gelu(sl2[25]), gelu(sl2[26]), gelu(sl2[27]));
    mrow[3] = make_float4(gelu(sl2[28]), gelu(sl2[29]), gelu(sl2[30]), gelu(sl2[31]));
#pragma unroll
    for (int qg = 0; qg < 4; qg++) {
        float t[12];
#pragma unroll
        for (int qq = 0; qq < 4; qq++) {
            const int q = qg * 4 + qq;
            const float g = sigm(sl2[q]);
            float be = 0.f;
#pragma unroll
            for (int p = 0; p < 16; p++) be += ms[p] * lWv1[p * 16 + q];
            float u0 = be * a0, u1 = be * a1, u2 = be * a2;
#pragma unroll
            for (int p = 0; p < 16; p++) {
                const float w = lWv1[(16 + p) * 16 + q];
                u0 += mv0[p] * w; u1 += mv1[p] * w; u2 += mv2[p] * w;
            }
            t[qq * 3 + 0] = u0 * g;
            t[qq * 3 + 1] = u1 * g;
            t[qq * 3 + 2] = u2 * g;
        }
        mrow[4 + qg * 3 + 0] = make_float4(t[0], t[1], t[2], t[3]);
        mrow[4 + qg * 3 + 1] = make_float4(t[4], t[5], t[6], t[7]);
        mrow[4 + qg * 3 + 2] = make_float4(t[8], t[9], t[10], t[11]);
    }
    mrow[16] = make_float4(a0, a1, a2, 0.f);
}

// Fused node kernel: gather (the old agg_kernel) + node update in one dispatch.
// 256 threads = 4 waves; block handles 64 nodes; wave w owns channel slice
// c/d in [4w,4w+4) (+16 on w3). The 87 MB msg gather (L3-resident: edge just
// wrote it) overlaps with the weight-broadcast latency chain instead of
// occupying its own dispatch. aggl[64][68] is union-allocated with part[21*256]
// (aggl is dead before part's first write; the lw-staging barrier inside the
// b-loop orders the transition).
__global__ __launch_bounds__(256, 2) void node_kernel(
    float* __restrict__ s, float4* __restrict__ v4,
    const float* __restrict__ msg, const int* __restrict__ offs,
    const float* __restrict__ cntb,
    const float* __restrict__ nWs, const float* __restrict__ nbs, const float* __restrict__ nWv,
    const float* __restrict__ fWs, const float* __restrict__ fbs, const float* __restrict__ fWv,
    float* __restrict__ out) {
    __shared__ float nsl[64 * 17];       // per-node ns, stride 17 (conflict-free)
    __shared__ float u[21 * 256];        // union: aggl[64][68] (4352) then part[21][256]
    __shared__ float lw[289 * 17 + 289]; // current b: Ws then Wv (20.8 KB)
    __shared__ float lf[256];            // fWs
    const int tid = threadIdx.x;
    const int lane = tid & 63;
    const int w = tid >> 6;
    const int n0 = blockIdx.x * 64 + lane;
    const bool valid = n0 < N_NODES;
    const int n = valid ? n0 : 0;
    const float inv = 1.0f / 319999.0f;  // 1/(E-1)

    if (tid < 256) lf[tid] = fWs[tid];

    // ---- fused gather: sum this block's msg rows into aggl[64][68] ----
    {
        const int nl = tid >> 2;           // node slot 0..63
        const int q = tid & 3;             // quad within the 17-float4 row
        const int gn0 = blockIdx.x * 64 + nl;
        const int gn = (gn0 < N_NODES) ? gn0 : 0;
        const int o0 = offs[gn];
        const int deg = (gn0 < N_NODES) ? (int)cntb[gn] : 0;
        float4 acc0 = make_float4(0.f, 0.f, 0.f, 0.f);
        float4 acc1 = acc0, acc2 = acc0, acc3 = acc0, acc4 = acc0;
        for (int r = 0; r < deg; r++) {
            const float4* row = (const float4*)(msg + (size_t)(o0 + r) * CH);
            const float4 t0 = row[q];
            const float4 t1 = row[q + 4];
            const float4 t2 = row[q + 8];
            const float4 t3 = row[q + 12];
            acc0.x += t0.x; acc0.y += t0.y; acc0.z += t0.z; acc0.w += t0.w;
            acc1.x += t1.x; acc1.y += t1.y; acc1.z += t1.z; acc1.w += t1.w;
            acc2.x += t2.x; acc2.y += t2.y; acc2.z += t2.z; acc2.w += t2.w;
            acc3.x += t3.x; acc3.y += t3.y; acc3.z += t3.z; acc3.w += t3.w;
            if (q == 0) {
                const float4 t4 = row[16];
                acc4.x += t4.x; acc4.y += t4.y; acc4.z += t4.z; acc4.w += t4.w;
            }
        }
        float4* rowl = (float4*)(u + nl * CH);  // 272B rows, 16B-aligned
        rowl[q] = acc0;
        rowl[q + 4] = acc1;
        rowl[q + 8] = acc2;
        rowl[q + 12] = acc3;
        if (q == 0) rowl[16] = acc4;
    }
    __syncthreads();

    const float cnt = cntb[n];
    const float f = inv / fmaxf(cnt, 1.0f);
    const float* ag = u + lane * CH;
    const int c0 = w * 4;
    const bool w3 = (w == 3);

    float yso[4];
#pragma unroll
    for (int k = 0; k < 4; k++) yso[k] = ag[c0 + k] * f;
    const float ys16 = cnt * f;
    float yvo[4][3];
#pragma unroll
    for (int k = 0; k < 4; k++) {
        const int d = c0 + k;
        yvo[k][0] = ag[16 + d * 3 + 0] * f;
        yvo[k][1] = ag[16 + d * 3 + 1] * f;
        yvo[k][2] = ag[16 + d * 3 + 2] * f;
    }
    float yv16[3] = {ag[64] * f, ag[65] * f, ag[66] * f};
    const float4 nvv = v4[n];
    float nv0 = nvv.x, nv1 = nvv.y, nv2 = nvv.z;

    if (w == 0) {
        const float4* srow = (const float4*)(s + n * 16);
        const float4 A = srow[0], B = srow[1], C = srow[2], D = srow[3];
        float* p = nsl + lane * 17;
        p[0] = A.x; p[1] = A.y; p[2] = A.z; p[3] = A.w;
        p[4] = B.x; p[5] = B.y; p[6] = B.z; p[7] = B.w;
        p[8] = C.x; p[9] = C.y; p[10] = C.z; p[11] = C.w;
        p[12] = D.x; p[13] = D.y; p[14] = D.z; p[15] = D.w;
    }

    float nsreg[16];
#pragma unroll 1
    for (int b = 0; b < 2; b++) {
        // stage this b's weights; the barrier also (a) orders the aggl->part
        // union transition and (b) protects the nsl staging above on b==0.
        for (int idx = tid; idx < 289 * 17; idx += 256) lw[idx] = nWs[b * 289 * 17 + idx];
        for (int idx = tid; idx < 289; idx += 256) lw[289 * 17 + idx] = nWv[b * 289 + idx];
        __syncthreads();
        const float* W = lw;
        const float* Wv = lw + 289 * 17;
        const float* bb = nbs + b * 17;
        float* part = u;
        float acc[17];
#pragma unroll
        for (int o = 0; o < 17; o++) acc[o] = (w == 0) ? bb[o] : 0.f;
        float gam[4] = {0.f, 0.f, 0.f, 0.f};
        float gam16 = 0.f;
#pragma unroll 2
        for (int a = 0; a < 16; a++) {
            const float xa = nsl[lane * 17 + a];
            const float* Wa = W + (a * 17 + c0) * 17;
#pragma unroll
            for (int k = 0; k < 4; k++) {
                const float cf = xa * yso[k];
#pragma unroll
                for (int o = 0; o < 17; o++) acc[o] += cf * Wa[k * 17 + o];
            }
            const float* Wva = Wv + a * 17 + c0;
#pragma unroll
            for (int k = 0; k < 4; k++) gam[k] += xa * Wva[k];
            if (w3) {
                const float cf = xa * ys16;
                const float* W16 = W + (a * 17 + 16) * 17;
#pragma unroll
                for (int o = 0; o < 17; o++) acc[o] += cf * W16[o];
                gam16 += xa * Wv[a * 17 + 16];
            }
        }
#pragma unroll
        for (int k = 0; k < 4; k++) {
            const int d = c0 + k;
            const float cf = nv0 * yvo[k][0] + nv1 * yvo[k][1] + nv2 * yvo[k][2];
            const float* Wp = W + (272 + d) * 17;
#pragma unroll
            for (int o = 0; o < 17; o++) acc[o] += cf * Wp[o];
        }
        if (w3) {
            const float cf = nv0 * yv16[0] + nv1 * yv16[1] + nv2 * yv16[2];
            const float* Wp = W + (272 + 16) * 17;
#pragma unroll
            for (int o = 0; o < 17; o++) acc[o] += cf * Wp[o];
        }
        float vl0 = 0.f, vl1 = 0.f, vl2 = 0.f, sc2 = 0.f;
#pragma unroll
        for (int k = 0; k < 4; k++) {
            vl0 += gam[k] * yvo[k][0]; vl1 += gam[k] * yvo[k][1]; vl2 += gam[k] * yvo[k][2];
            sc2 += yso[k] * Wv[272 + c0 + k];
        }
        if (w3) {
            vl0 += gam16 * yv16[0]; vl1 += gam16 * yv16[1]; vl2 += gam16 * yv16[2];
            sc2 += ys16 * Wv[272 + 16];
        }
#pragma unroll
        for (int o = 0; o < 17; o++) part[o * 256 + tid] = acc[o];
        part[17 * 256 + tid] = vl0;
        part[18 * 256 + tid] = vl1;
        part[19 * 256 + tid] = vl2;
        part[20 * 256 + tid] = sc2;
        __syncthreads();
        float tot[21];
#pragma unroll
        for (int t = 0; t < 21; t++)
            tot[t] = part[t * 256 + lane] + part[t * 256 + 64 + lane] +
                     part[t * 256 + 128 + lane] + part[t * 256 + 192 + lane];
        const float g = sigm(tot[0]);
#pragma unroll
        for (int a = 0; a < 16; a++) nsreg[a] = gelu(tot[1 + a]);
        const float nx = (tot[17] + tot[20] * nv0) * g;
        const float ny = (tot[18] + tot[20] * nv1) * g;
        const float nz = (tot[19] + tot[20] * nv2) * g;
        nv0 = nx; nv1 = ny; nv2 = nz;
        if (b == 0 && w == 0) {
            float* p = nsl + lane * 17;
#pragma unroll
            for (int a = 0; a < 16; a++) p[a] = nsreg[a];
        }
        __syncthreads();
    }
    float so[16];
#pragma unroll
    for (int a = 0; a < 16; a++) so[a] = fbs[a];
#pragma unroll
    for (int p = 0; p < 16; p++) {
        const float x = nsreg[p];
#pragma unroll
        for (int a = 0; a < 16; a++) so[a] += x * lf[p * 16 + a];
    }
    if (valid && w == 0) {
        const float fw = fWv[0];
        float sn[16];
#pragma unroll
        for (int a = 0; a < 16; a++) { sn[a] = s[n * 16 + a] + so[a]; }
#pragma unroll
        for (int a = 0; a < 16; a++) s[n * 16 + a] = sn[a];
        const float w0o = nvv.x + nv0 * fw;
        const float w1o = nvv.y + nv1 * fw;
        const float w2o = nvv.z + nv2 * fw;
        v4[n] = make_float4(w0o, w1o, w2o, 0.f);
        if (out) {
#pragma unroll
            for (int a = 0; a < 16; a++) out[n * 19 + a] = sn[a];
            out[n * 19 + 16] = w0o;
            out[n * 19 + 17] = w1o;
            out[n * 19 + 18] = w2o;
        }
    }
}

extern "C" void kernel_launch(void* const* d_in, const int* in_sizes, int n_in,
                              void* d_out, int out_size, void* d_ws, size_t ws_size,
                              hipStream_t stream) {
    const float* node_scalars = (const float*)d_in[0];
    const float* node_pos = (const float*)d_in[1];
    const int* senders = (const int*)d_in[2];
    const int* receivers = (const int*)d_in[3];
    const float* eWs0 = (const float*)d_in[4];
    const float* ebs0 = (const float*)d_in[5];
    const float* eWv0 = (const float*)d_in[6];
    const float* eWs1 = (const float*)d_in[7];
    const float* ebs1 = (const float*)d_in[8];
    const float* eWv1 = (const float*)d_in[9];
    const float* nWs = (const float*)d_in[10];
    const float* nbs = (const float*)d_in[11];
    const float* nWv = (const float*)d_in[12];
    const float* fWs = (const float*)d_in[13];
    const float* fbs = (const float*)d_in[14];
    const float* fWv = (const float*)d_in[15];

    float* ws = (float*)d_ws;
    float* s = ws;                        // N*16
    float* v = s + N_NODES * 16;          // N*4 (float4)
    float* cnt = v + N_NODES * 4;         // N
    int* offs = (int*)(cnt + N_NODES);    // N
    int* cursor = offs + N_NODES;         // N
    int* perm = cursor + N_NODES;         // E
    float* msg = (float*)(perm + N_EDGES);// E*CH (87 MB)
    float* out = (float*)d_out;
    float4* v4 = (float4*)v;

    init_kernel<<<(N_NODES * 16 + 255) / 256, 256, 0, stream>>>(node_scalars, node_pos, s, v4, cnt);
    count_kernel<<<(N_EDGES + 255) / 256, 256, 0, stream>>>(receivers, cnt);
    scan_kernel<<<1, 1024, 0, stream>>>(cnt, offs, cursor);
    scatter_kernel<<<(N_EDGES + 255) / 256, 256, 0, stream>>>(receivers, offs, cursor, perm);
    for (int t = 0; t < 3; t++) {
        edge_compute_kernel<<<N_EDGES / 256, 256, 0, stream>>>(
            (const float4*)s, (const float4*)v4, senders, receivers, perm,
            eWs0 + t * 34 * 32, ebs0 + t * 32, eWv0 + t * 34 * 16,
            eWs1 + t * 32 * 32, ebs1 + t * 32, eWv1 + t * 32 * 16,
            msg);
        node_kernel<<<(N_NODES + 63) / 64, 256, 0, stream>>>(
            s, v4, msg, offs, cnt,
            nWs + t * 2 * 289 * 17, nbs + t * 2 * 17, nWv + t * 2 * 289,
            fWs + t * 256, fbs + t * 16, fWv + t,
            (t == 2) ? out : nullptr);
    }
}